// Round 1
// baseline (476.241 us; speedup 1.0000x reference)
//
#include <hip/hip_runtime.h>
#include <math.h>

#define NPTS 65536
#define NSAMP 16
#define CH 64
#define NROWS (NPTS*NSAMP)
#define BN_EPS 1e-5f

// workspace layout (float offsets)
#define OFF_S3   0            // sum3[3], sq3[3]
#define OFF_F3   8            // scale3[3], shift3[3]
#define OFF_S64  16           // sum64[64] @16, sq64[64] @80
#define OFF_F64  144          // scale64[64] @144, shift64[64] @208
#define OFF_S8   272          // sum8[8], sq8[8]
#define OFF_F8   288          // scale8[8], shift8[8]
#define OFF_XQ   512
#define OFF_XK   (OFF_XQ + NPTS*CH)
#define OFF_XV   (OFF_XK + NPTS*CH)
#define OFF_PR1  (OFF_XV + NPTS*CH)
#define OFF_W2   (OFF_PR1 + NROWS*3)
// total floats: OFF_W2 + NROWS*8 = 24,117,760  (~92 MB)

__device__ __forceinline__ float wave_sum(float v){
#pragma unroll
  for (int m = 32; m > 0; m >>= 1) v += __shfl_xor(v, m);
  return v;
}

__device__ __forceinline__ float f4get(const float4& v, int i){
  return i == 0 ? v.x : (i == 1 ? v.y : (i == 2 ? v.z : v.w));
}

__global__ void k_zero(float* __restrict__ ws){
  if (threadIdx.x < 512) ws[threadIdx.x] = 0.0f;
}

// q/k/v projections: one thread per point, one weight matrix per blockIdx.y
__global__ __launch_bounds__(256) void k_proj(const float* __restrict__ x,
    const float* __restrict__ W0, const float* __restrict__ b0,
    const float* __restrict__ W1, const float* __restrict__ b1,
    const float* __restrict__ W2, const float* __restrict__ b2,
    float* __restrict__ ws)
{
  int n = blockIdx.x * blockDim.x + threadIdx.x;
  const float* W; const float* b; float* out;
  if (blockIdx.y == 0)      { W = W0; b = b0; out = ws + OFF_XQ; }
  else if (blockIdx.y == 1) { W = W1; b = b1; out = ws + OFF_XK; }
  else                      { W = W2; b = b2; out = ws + OFF_XV; }

  float4 xr[16];
  const float4* xp = (const float4*)(x + (size_t)n * CH);
#pragma unroll
  for (int i = 0; i < 16; i++) xr[i] = xp[i];

  float4* op = (float4*)(out + (size_t)n * CH);
#pragma unroll 1
  for (int o4 = 0; o4 < 16; o4++){
    float a[4];
#pragma unroll
    for (int oo = 0; oo < 4; oo++){
      int o = o4 * 4 + oo;
      float acc = b[o];
      const float4* wp = (const float4*)(W + o * CH);
#pragma unroll
      for (int i = 0; i < 16; i++){
        float4 w4 = wp[i];
        acc += xr[i].x * w4.x + xr[i].y * w4.y + xr[i].z * w4.z + xr[i].w * w4.w;
      }
      a[oo] = acc;
    }
    float4 st; st.x = a[0]; st.y = a[1]; st.z = a[2]; st.w = a[3];
    op[o4] = st;
  }
}

// p_r stage 1 (Linear(3,3)) + BN3 partial sums
__global__ __launch_bounds__(256) void k_pr1(const float* __restrict__ p,
    const int* __restrict__ idx, const float* __restrict__ Wp1,
    const float* __restrict__ bp1, float* __restrict__ ws)
{
  float* pr1 = ws + OFF_PR1;
  float w00=Wp1[0],w01=Wp1[1],w02=Wp1[2];
  float w10=Wp1[3],w11=Wp1[4],w12=Wp1[5];
  float w20=Wp1[6],w21=Wp1[7],w22=Wp1[8];
  float b0=bp1[0],b1=bp1[1],b2=bp1[2];
  float s0=0,s1=0,s2=0,q0=0,q1=0,q2=0;
  int stride = gridDim.x * blockDim.x;
  for (int r = blockIdx.x*blockDim.x + threadIdx.x; r < NROWS; r += stride){
    int n = r >> 4;
    int iv = idx[r];
    float dx = p[iv*3+0] - p[n*3+0];
    float dy = p[iv*3+1] - p[n*3+1];
    float dz = p[iv*3+2] - p[n*3+2];
    float v0 = b0 + dx*w00 + dy*w01 + dz*w02;
    float v1 = b1 + dx*w10 + dy*w11 + dz*w12;
    float v2 = b2 + dx*w20 + dy*w21 + dz*w22;
    pr1[r*3+0]=v0; pr1[r*3+1]=v1; pr1[r*3+2]=v2;
    s0+=v0; s1+=v1; s2+=v2;
    q0+=v0*v0; q1+=v1*v1; q2+=v2*v2;
  }
  s0=wave_sum(s0); s1=wave_sum(s1); s2=wave_sum(s2);
  q0=wave_sum(q0); q1=wave_sum(q1); q2=wave_sum(q2);
  __shared__ float lds[4][6];
  int lane = threadIdx.x & 63, wv = threadIdx.x >> 6;
  if (lane == 0){
    lds[wv][0]=s0; lds[wv][1]=s1; lds[wv][2]=s2;
    lds[wv][3]=q0; lds[wv][4]=q1; lds[wv][5]=q2;
  }
  __syncthreads();
  if (threadIdx.x < 6){
    float v = lds[0][threadIdx.x]+lds[1][threadIdx.x]+lds[2][threadIdx.x]+lds[3][threadIdx.x];
    atomicAdd(ws + OFF_S3 + threadIdx.x, v);
  }
}

// BN finalize: scale = g*rsqrt(var+eps), shift = beta - mean*scale
__global__ void k_finalize(const float* __restrict__ sums, float* __restrict__ outf,
                           const float* __restrict__ g, const float* __restrict__ beta, int nch)
{
  int t = threadIdx.x;
  if (t < nch){
    float invM = 1.0f / (float)NROWS;
    float mean = sums[t] * invM;
    float var  = sums[nch + t] * invM - mean * mean;
    float rs   = rsqrtf(var + BN_EPS);
    float sc   = g[t] * rs;
    outf[t] = sc;
    outf[nch + t] = beta[t] - mean * sc;
  }
}

// BN64 stats over w_pre = xk[idx] - xq + p_r2 (wave per row, lane = channel)
__global__ __launch_bounds__(256) void k_stats64(const int* __restrict__ idx,
    const float* __restrict__ xq, const float* __restrict__ xk,
    const float* __restrict__ pr1, const float* __restrict__ f3,
    const float* __restrict__ Wp2, const float* __restrict__ bp2,
    float* __restrict__ s64)
{
  int lane = threadIdx.x & 63, wv = threadIdx.x >> 6;
  float wpa = Wp2[lane*3+0], wpb = Wp2[lane*3+1], wpc = Wp2[lane*3+2];
  float bp  = bp2[lane];
  float sc0=f3[0], sc1=f3[1], sc2=f3[2], sh0=f3[3], sh1=f3[4], sh2=f3[5];
  float accs=0.0f, accq=0.0f;
  int wave_id = blockIdx.x*4 + wv;
  int rpw = NROWS / (gridDim.x * 4);
  int row0 = wave_id * rpw;
  for (int rr = 0; rr < rpw; rr++){
    int r = __builtin_amdgcn_readfirstlane(row0 + rr);
    int iv = idx[r];
    int n  = r >> 4;
    float a0 = pr1[r*3+0], a1 = pr1[r*3+1], a2 = pr1[r*3+2];
    float rb0 = fmaxf(a0*sc0+sh0, 0.0f);
    float rb1 = fmaxf(a1*sc1+sh1, 0.0f);
    float rb2 = fmaxf(a2*sc2+sh2, 0.0f);
    float pr2 = bp + rb0*wpa + rb1*wpb + rb2*wpc;
    float w = xk[(size_t)iv*CH + lane] - xq[(size_t)n*CH + lane] + pr2;
    accs += w; accq += w*w;
  }
  __shared__ float lds[4][128];
  lds[wv][lane] = accs; lds[wv][64+lane] = accq;
  __syncthreads();
  if (threadIdx.x < 128){
    float v = lds[0][threadIdx.x]+lds[1][threadIdx.x]+lds[2][threadIdx.x]+lds[3][threadIdx.x];
    atomicAdd(s64 + threadIdx.x, v);
  }
}

// w2 = relu(bn64(w_pre)) @ Ww1^T + bw1  (thread per row) + BN8 partial sums
__global__ __launch_bounds__(256) void k_w2(const int* __restrict__ idx,
    const float* __restrict__ xq, const float* __restrict__ xk,
    const float* __restrict__ pr1, const float* __restrict__ f3,
    const float* __restrict__ f64, const float* __restrict__ Wp2,
    const float* __restrict__ bp2, const float* __restrict__ Ww1,
    const float* __restrict__ bw1, float* __restrict__ w2o,
    float* __restrict__ s8out)
{
  float sc30=f3[0], sc31=f3[1], sc32=f3[2], sh30=f3[3], sh31=f3[4], sh32=f3[5];
  float s8[8], q8[8];
#pragma unroll
  for (int o = 0; o < 8; o++){ s8[o]=0.0f; q8[o]=0.0f; }

  int base = blockIdx.x * 1024;
#pragma unroll 1
  for (int k = 0; k < 4; k++){
    int r = base + k*256 + threadIdx.x;
    int n = r >> 4;
    int iv = idx[r];
    float a0 = pr1[r*3+0], a1 = pr1[r*3+1], a2 = pr1[r*3+2];
    float rb0 = fmaxf(a0*sc30+sh30, 0.0f);
    float rb1 = fmaxf(a1*sc31+sh31, 0.0f);
    float rb2 = fmaxf(a2*sc32+sh32, 0.0f);
    float acc[8];
#pragma unroll
    for (int o = 0; o < 8; o++) acc[o] = bw1[o];
    const float4* xkr = (const float4*)(xk + (size_t)iv*CH);
    const float4* xqr = (const float4*)(xq + (size_t)n*CH);
#pragma unroll
    for (int c4 = 0; c4 < 16; c4++){
      float4 kk = xkr[c4];
      float4 qq = xqr[c4];
#pragma unroll
      for (int cc = 0; cc < 4; cc++){
        int c = c4*4 + cc;
        float pr2 = bp2[c] + rb0*Wp2[c*3+0] + rb1*Wp2[c*3+1] + rb2*Wp2[c*3+2];
        float w = f4get(kk,cc) - f4get(qq,cc) + pr2;
        float rb = fmaxf(w*f64[c] + f64[64+c], 0.0f);
#pragma unroll
        for (int o = 0; o < 8; o++) acc[o] += rb * Ww1[o*CH + c];
      }
    }
    float4 st0, st1;
    st0.x=acc[0]; st0.y=acc[1]; st0.z=acc[2]; st0.w=acc[3];
    st1.x=acc[4]; st1.y=acc[5]; st1.z=acc[6]; st1.w=acc[7];
    float4* wp = (float4*)(w2o + (size_t)r*8);
    wp[0]=st0; wp[1]=st1;
#pragma unroll
    for (int o = 0; o < 8; o++){ s8[o]+=acc[o]; q8[o]+=acc[o]*acc[o]; }
  }
#pragma unroll
  for (int o = 0; o < 8; o++){ s8[o]=wave_sum(s8[o]); q8[o]=wave_sum(q8[o]); }
  __shared__ float lds[4][16];
  int lane = threadIdx.x & 63, wv = threadIdx.x >> 6;
  if (lane == 0){
#pragma unroll
    for (int o = 0; o < 8; o++){ lds[wv][o]=s8[o]; lds[wv][8+o]=q8[o]; }
  }
  __syncthreads();
  if (threadIdx.x < 16){
    float v = lds[0][threadIdx.x]+lds[1][threadIdx.x]+lds[2][threadIdx.x]+lds[3][threadIdx.x];
    atomicAdd(s8out + threadIdx.x, v);
  }
}

// final: w3 = relu(bn8(w2)) @ Ww2^T + bw2 ; softmax over neighbors ; out = sum_j (xv+p_r2)*w
__global__ __launch_bounds__(256) void k_out(const int* __restrict__ idx,
    const float* __restrict__ xv, const float* __restrict__ pr1,
    const float* __restrict__ w2, const float* __restrict__ f3,
    const float* __restrict__ f8, const float* __restrict__ Wp2,
    const float* __restrict__ bp2, const float* __restrict__ Ww2,
    const float* __restrict__ bw2, float* __restrict__ out)
{
  int lane = threadIdx.x & 63, wv = threadIdx.x >> 6;
  int n = __builtin_amdgcn_readfirstlane(blockIdx.x*4 + wv);
  int cp = lane & 7;     // weight channel c' = c % 8
  int jg = lane >> 3;    // this lane computes w3 for j = jg and j = jg+8

  float wpa = Wp2[lane*3+0], wpb = Wp2[lane*3+1], wpc = Wp2[lane*3+2];
  float bp  = bp2[lane];
  float ww2_[8];
#pragma unroll
  for (int k = 0; k < 8; k++) ww2_[k] = Ww2[cp*8 + k];
  float bw = bw2[cp];
  float sc8[8], sh8[8];
#pragma unroll
  for (int k = 0; k < 8; k++){ sc8[k]=f8[k]; sh8[k]=f8[8+k]; }
  float sc30=f3[0], sc31=f3[1], sc32=f3[2], sh30=f3[3], sh31=f3[4], sh32=f3[5];

  // phase 1: w3 for (jg, cp) and (jg+8, cp)
  const float4* ra = (const float4*)(w2 + ((size_t)n*NSAMP + jg)*8);
  const float4* rb_ = (const float4*)(w2 + ((size_t)n*NSAMP + jg + 8)*8);
  float4 A0 = ra[0],  A1 = ra[1];
  float4 B0 = rb_[0], B1 = rb_[1];
  float w3a = bw, w3b = bw;
#pragma unroll
  for (int k = 0; k < 8; k++){
    float va = (k < 4) ? f4get(A0,k) : f4get(A1,k-4);
    float vb = (k < 4) ? f4get(B0,k) : f4get(B1,k-4);
    float rba = fmaxf(va*sc8[k]+sh8[k], 0.0f);
    float rbb = fmaxf(vb*sc8[k]+sh8[k], 0.0f);
    w3a += rba * ww2_[k];
    w3b += rbb * ww2_[k];
  }

  // softmax over 16 neighbors: values for fixed cp live at lanes stride-8
  float m = fmaxf(w3a, w3b);
#pragma unroll
  for (int mask = 8; mask <= 32; mask <<= 1) m = fmaxf(m, __shfl_xor(m, mask));
  float ea = expf(w3a - m), eb = expf(w3b - m);
  float ssum = ea + eb;
#pragma unroll
  for (int mask = 8; mask <= 32; mask <<= 1) ssum += __shfl_xor(ssum, mask);
  float inv = 1.0f / ssum;
  ea *= inv; eb *= inv;

  // phase 2: accumulate out[n, lane]
  float oacc = 0.0f;
#pragma unroll 1
  for (int j = 0; j < NSAMP; j++){
    float wn = __shfl(j < 8 ? ea : eb, ((j & 7) << 3) | cp);
    int iv = idx[n*NSAMP + j];
    int rr = n*NSAMP + j;
    float a0 = pr1[rr*3+0], a1 = pr1[rr*3+1], a2 = pr1[rr*3+2];
    float rb0 = fmaxf(a0*sc30+sh30, 0.0f);
    float rb1 = fmaxf(a1*sc31+sh31, 0.0f);
    float rb2 = fmaxf(a2*sc32+sh32, 0.0f);
    float pr2 = bp + rb0*wpa + rb1*wpb + rb2*wpc;
    float xvv = xv[(size_t)iv*CH + lane];
    oacc += (xvv + pr2) * wn;
  }
  out[(size_t)n*CH + lane] = oacc;
}

extern "C" void kernel_launch(void* const* d_in, const int* in_sizes, int n_in,
                              void* d_out, int out_size, void* d_ws, size_t ws_size,
                              hipStream_t stream)
{
  const float* p    = (const float*)d_in[0];
  const float* x    = (const float*)d_in[1];
  const int*   idx  = (const int*)d_in[2];
  const float* Wq   = (const float*)d_in[3];
  const float* bq   = (const float*)d_in[4];
  const float* Wk   = (const float*)d_in[5];
  const float* bk   = (const float*)d_in[6];
  const float* Wv   = (const float*)d_in[7];
  const float* bv   = (const float*)d_in[8];
  const float* Wp1  = (const float*)d_in[9];
  const float* bp1  = (const float*)d_in[10];
  const float* gp   = (const float*)d_in[11];
  const float* betap= (const float*)d_in[12];
  const float* Wp2  = (const float*)d_in[13];
  const float* bp2  = (const float*)d_in[14];
  const float* gw1  = (const float*)d_in[15];
  const float* betaw1=(const float*)d_in[16];
  const float* Ww1  = (const float*)d_in[17];
  const float* bw1  = (const float*)d_in[18];
  const float* gw2  = (const float*)d_in[19];
  const float* betaw2=(const float*)d_in[20];
  const float* Ww2  = (const float*)d_in[21];
  const float* bw2  = (const float*)d_in[22];
  float* ws  = (float*)d_ws;
  float* out = (float*)d_out;

  k_zero<<<dim3(1), dim3(512), 0, stream>>>(ws);
  k_proj<<<dim3(NPTS/256, 3), dim3(256), 0, stream>>>(x, Wq,bq, Wk,bk, Wv,bv, ws);
  k_pr1<<<dim3(512), dim3(256), 0, stream>>>(p, idx, Wp1, bp1, ws);
  k_finalize<<<dim3(1), dim3(64), 0, stream>>>(ws+OFF_S3, ws+OFF_F3, gp, betap, 3);
  k_stats64<<<dim3(2048), dim3(256), 0, stream>>>(idx, ws+OFF_XQ, ws+OFF_XK,
      ws+OFF_PR1, ws+OFF_F3, Wp2, bp2, ws+OFF_S64);
  k_finalize<<<dim3(1), dim3(64), 0, stream>>>(ws+OFF_S64, ws+OFF_F64, gw1, betaw1, 64);
  k_w2<<<dim3(1024), dim3(256), 0, stream>>>(idx, ws+OFF_XQ, ws+OFF_XK, ws+OFF_PR1,
      ws+OFF_F3, ws+OFF_F64, Wp2, bp2, Ww1, bw1, ws+OFF_W2, ws+OFF_S8);
  k_finalize<<<dim3(1), dim3(64), 0, stream>>>(ws+OFF_S8, ws+OFF_F8, gw2, betaw2, 8);
  k_out<<<dim3(NPTS/4), dim3(256), 0, stream>>>(idx, ws+OFF_XV, ws+OFF_PR1, ws+OFF_W2,
      ws+OFF_F3, ws+OFF_F8, Wp2, bp2, Ww2, bw2, out);
}